// Round 1
// baseline (791.834 us; speedup 1.0000x reference)
//
#include <hip/hip_runtime.h>
#include <math.h>

#define SEQ    2048
#define DM     512
#define DH     64
#define NHASH  4
#define NBUCK  512
#define NBM    64            // BATCH*HEADS
#define SELF_VAL (-5e4f)

// ---------------- K1: fused qk/v GEMM (f32) ----------------
// A = queries (16384 x 512), B = [Wqk | Wv] (512 x 1024)
// writes qk, v in head-major layout: [(b*8+h)][t][dd]
__global__ __launch_bounds__(256) void k_gemm_qkv(
    const float* __restrict__ Q, const float* __restrict__ Wqk,
    const float* __restrict__ Wv, float* __restrict__ qk, float* __restrict__ vv)
{
    __shared__ float As[32][68];
    __shared__ float Bs[32][68];
    const int bi = blockIdx.x;
    const int nt = bi & 15;          // 16 col tiles over N=1024
    const int mt = bi >> 4;          // 256 row tiles over M=16384
    const int m0 = mt * 64, n0 = nt * 64;
    const int tid = threadIdx.x;
    const int ty = tid >> 4, tx = tid & 15;
    const float* Bsrc = (n0 < 512) ? (Wqk + n0) : (Wv + (n0 - 512));
    float acc[4][4] = {};
    for (int k0 = 0; k0 < 512; k0 += 32) {
        #pragma unroll
        for (int c = 0; c < 2; c++) {
            int e = tid * 2 + c;
            int r = e >> 3, kq = e & 7;
            float4 a4 = *(const float4*)(Q + (size_t)(m0 + r) * 512 + k0 + kq * 4);
            As[kq*4+0][r] = a4.x; As[kq*4+1][r] = a4.y;
            As[kq*4+2][r] = a4.z; As[kq*4+3][r] = a4.w;
            int kk = e >> 4, nq = e & 15;
            float4 b4 = *(const float4*)(Bsrc + (size_t)(k0 + kk) * 512 + nq * 4);
            *(float4*)&Bs[kk][nq*4] = b4;
        }
        __syncthreads();
        #pragma unroll
        for (int kk = 0; kk < 32; kk++) {
            float4 a4 = *(float4*)&As[kk][ty*4];
            float4 b4 = *(float4*)&Bs[kk][tx*4];
            float a_[4] = {a4.x, a4.y, a4.z, a4.w};
            float b_[4] = {b4.x, b4.y, b4.z, b4.w};
            #pragma unroll
            for (int i = 0; i < 4; i++)
                #pragma unroll
                for (int j = 0; j < 4; j++)
                    acc[i][j] += a_[i] * b_[j];
        }
        __syncthreads();
    }
    #pragma unroll
    for (int ri = 0; ri < 4; ri++) {
        int row = m0 + ty * 4 + ri;
        int b = row >> 11, t = row & 2047;
        float4 r4 = make_float4(acc[ri][0], acc[ri][1], acc[ri][2], acc[ri][3]);
        int dd = tx * 4;
        if (n0 < 512) {
            int h = n0 >> 6;
            *(float4*)(qk + ((size_t)((b*8+h)*2048 + t))*64 + dd) = r4;
        } else {
            int h = (n0 - 512) >> 6;
            *(float4*)(vv + ((size_t)((b*8+h)*2048 + t))*64 + dd) = r4;
        }
    }
}

// ---------------- K1b: reciprocal row norms of qk ----------------
__global__ __launch_bounds__(256) void k_rnorm(const float* __restrict__ qk,
                                               float* __restrict__ rnorm)
{
    int w = threadIdx.x >> 6, lane = threadIdx.x & 63;
    int row = blockIdx.x * 4 + w;            // 0..131071  (bm*2048+t)
    float x = qk[(size_t)row * 64 + lane];
    float s = x * x;
    #pragma unroll
    for (int d = 1; d < 64; d <<= 1) s += __shfl_xor(s, d);
    if (lane == 0) rnorm[row] = 1.0f / fmaxf(sqrtf(s), 1e-12f);
}

// ---------------- K2: hash projection + signed argmax ----------------
__global__ __launch_bounds__(256) void k_hash(const float* __restrict__ qk,
    const float* __restrict__ rot, unsigned* __restrict__ buckets)
{
    __shared__ float Qs[64][68];
    __shared__ float Rs[64][68];
    const int bm = blockIdx.x >> 5;
    const int t0 = (blockIdx.x & 31) * 64;
    const int tid = threadIdx.x;
    const int ty = tid >> 4, tx = tid & 15;
    // stage Q tile transposed: Qs[f][token]
    #pragma unroll
    for (int c = 0; c < 4; c++) {
        int e = tid * 4 + c;                 // 0..1023
        int j = e >> 4, fq = e & 15;
        float4 q4 = *(const float4*)(qk + ((size_t)(bm*2048 + t0 + j))*64 + fq*4);
        Qs[fq*4+0][j] = q4.x; Qs[fq*4+1][j] = q4.y;
        Qs[fq*4+2][j] = q4.z; Qs[fq*4+3][j] = q4.w;
    }
    for (int h = 0; h < NHASH; h++) {
        float bv[4];  unsigned bidx[4];
        #pragma unroll
        for (int i = 0; i < 4; i++) { bv[i] = -3.402823466e38f; bidx[i] = 0; }
        for (int cb = 0; cb < 4; cb++) {
            __syncthreads();
            #pragma unroll
            for (int c = 0; c < 4; c++) {
                int e = tid * 4 + c;
                int f = e >> 4, iq = e & 15;
                float4 r4 = *(const float4*)(rot + ((size_t)(f*4 + h))*256 + cb*64 + iq*4);
                *(float4*)&Rs[f][iq*4] = r4;
            }
            __syncthreads();
            float acc[4][4] = {};
            #pragma unroll 8
            for (int f = 0; f < 64; f++) {
                float4 q4 = *(float4*)&Qs[f][ty*4];
                float4 r4 = *(float4*)&Rs[f][tx*4];
                float a_[4] = {q4.x, q4.y, q4.z, q4.w};
                float b_[4] = {r4.x, r4.y, r4.z, r4.w};
                #pragma unroll
                for (int i = 0; i < 4; i++)
                    #pragma unroll
                    for (int j = 0; j < 4; j++)
                        acc[i][j] += a_[i] * b_[j];
            }
            #pragma unroll
            for (int i = 0; i < 4; i++) {
                #pragma unroll
                for (int c2 = 0; c2 < 4; c2++) {
                    unsigned idx = (unsigned)(cb*64 + tx*4 + c2);
                    float vvv = acc[i][c2];
                    if (vvv > bv[i] || (vvv == bv[i] && idx < bidx[i])) { bv[i] = vvv; bidx[i] = idx; }
                    float nv = -vvv; unsigned nidx = 256u + idx;
                    if (nv > bv[i] || (nv == bv[i] && nidx < bidx[i])) { bv[i] = nv; bidx[i] = nidx; }
                }
            }
        }
        __syncthreads();
        float* flat = &Rs[0][0];
        float* redv = flat;                       // 1024 floats
        unsigned* redi = (unsigned*)(flat + 1024);// 1024 u32
        #pragma unroll
        for (int i = 0; i < 4; i++) {
            int j = ty*4 + i;
            redv[j*16 + tx] = bv[i];
            redi[j*16 + tx] = bidx[i];
        }
        __syncthreads();
        if (tid < 64) {
            int j = tid;
            float best = -3.402823466e38f; unsigned besti = 0;
            for (int x = 0; x < 16; x++) {
                float vvv = redv[j*16 + x]; unsigned ii = redi[j*16 + x];
                if (vvv > best || (vvv == best && ii < besti)) { best = vvv; besti = ii; }
            }
            buckets[((size_t)(bm*4 + h))*2048 + t0 + j] = besti;
        }
        __syncthreads();
    }
}

// ---------------- K3: stable counting sort per (bm,hash) ----------------
__global__ __launch_bounds__(256) void k_sort(const unsigned* __restrict__ buckets,
                                              unsigned* __restrict__ st)
{
    __shared__ unsigned whist[4][512];
    __shared__ unsigned baseb[512];
    const int seg = blockIdx.x;                  // bm*4+h
    const unsigned* bk = buckets + (size_t)seg * 2048;
    unsigned* out = st + (size_t)seg * 2048;
    const int tid = threadIdx.x, w = tid >> 6, lane = tid & 63;
    for (int b = tid; b < 2048; b += 256) ((unsigned*)whist)[b] = 0u;
    __syncthreads();
    unsigned myb[8];
    #pragma unroll
    for (int r = 0; r < 8; r++) {
        int pos = w*512 + r*64 + lane;
        myb[r] = bk[pos];
        atomicAdd(&whist[w][myb[r]], 1u);
    }
    __syncthreads();
    for (int b = tid; b < 512; b += 256) {
        unsigned p = 0;
        #pragma unroll
        for (int ww = 0; ww < 4; ww++) { unsigned t = whist[ww][b]; whist[ww][b] = p; p += t; }
        baseb[b] = p;
    }
    __syncthreads();
    if (tid == 0) {
        unsigned run = 0;
        for (int b = 0; b < 512; b++) { unsigned t = baseb[b]; baseb[b] = run; run += t; }
    }
    __syncthreads();
    for (int b = tid; b < 512; b += 256) {
        unsigned bb = baseb[b];
        #pragma unroll
        for (int ww = 0; ww < 4; ww++) whist[ww][b] += bb;
    }
    __syncthreads();
    for (int r = 0; r < 8; r++) {
        unsigned b = myb[r];
        int pos = w*512 + r*64 + lane;
        unsigned base = whist[w][b];             // read before this round's bumps
        unsigned rank = 0;
        for (int j = 0; j < 64; j++) {
            unsigned bj = __shfl(b, j);
            rank += (j < lane && bj == b) ? 1u : 0u;
        }
        out[base + rank] = (unsigned)pos;
        atomicAdd(&whist[w][b], 1u);
    }
}

// ---------------- K4: chunked LSH attention ----------------
// block: one (bm, h, strip of 16 chunks = 64 q tokens) + 4-token halo
__global__ __launch_bounds__(256) void k_attn(const float* __restrict__ qk,
    const float* __restrict__ vv, const float* __restrict__ rnorm,
    const unsigned* __restrict__ st, float* __restrict__ oh,
    float* __restrict__ logits)
{
    __shared__ float qs[68][68];
    __shared__ float vs[68][68];
    __shared__ unsigned P[68];
    __shared__ float rn[68];
    const int sid = blockIdx.x;
    const int stripi = sid & 31;
    const int seg = sid >> 5;
    const int bm = seg >> 2, h = seg & 3;
    const int G0 = (h*512 + stripi*16) * 4;      // first q slot (global, 0..8191)
    const int tid = threadIdx.x;
    for (int j = tid; j < 68; j += 256) {
        int G = (G0 - 4 + j) & 8191;
        int hg = G >> 11, sg = G & 2047;
        unsigned tok = st[((size_t)(bm*4 + hg))*2048 + sg];
        P[j] = tok;
        rn[j] = rnorm[bm*2048 + (int)tok];
    }
    __syncthreads();
    for (int e = tid; e < 68*16; e += 256) {
        int j = e >> 4, fq = e & 15;
        unsigned tok = P[j];
        size_t base = ((size_t)(bm*2048 + (int)tok))*64 + fq*4;
        *(float4*)&qs[j][fq*4] = *(const float4*)(qk + base);
        *(float4*)&vs[j][fq*4] = *(const float4*)(vv + base);
    }
    __syncthreads();
    const int w = tid >> 6, lane = tid & 63;
    const int half = lane >> 5, qi = (lane >> 3) & 3, jj = lane & 7;
    const int fb = lane & 7;
    for (int cp = 0; cp < 2; cp++) {
        int c = w*4 + cp*2 + half;               // local chunk 0..15
        int jq = 4 + c*4 + qi;
        int jk = c*4 + jj;
        float dot = 0.f;
        #pragma unroll
        for (int fq = 0; fq < 16; fq++) {
            float4 q4 = *(float4*)&qs[jq][fq*4];
            float4 k4 = *(float4*)&qs[jk][fq*4];
            dot += q4.x*k4.x + q4.y*k4.y + q4.z*k4.z + q4.w*k4.w;
        }
        dot *= 0.125f * rn[jk];
        if (P[jq] == P[jk]) dot = SELF_VAL;
        float m = dot;
        m = fmaxf(m, __shfl_xor(m, 1));
        m = fmaxf(m, __shfl_xor(m, 2));
        m = fmaxf(m, __shfl_xor(m, 4));
        float ex = expf(dot - m);
        float s = ex;
        s += __shfl_xor(s, 1); s += __shfl_xor(s, 2); s += __shfl_xor(s, 4);
        float lse = m + logf(s);
        float p = expf(dot - lse);
        unsigned tq = P[jq];
        if (jj == 0) logits[((size_t)(bm*4 + h))*2048 + tq] = lse;
        float a0=0,a1=0,a2=0,a3=0,a4a=0,a5=0,a6=0,a7=0;
        #pragma unroll
        for (int j2 = 0; j2 < 8; j2++) {
            float pj = __shfl(p, (lane & 0x38) | j2);
            float4 va = *(float4*)&vs[c*4 + j2][fb*8];
            float4 vb = *(float4*)&vs[c*4 + j2][fb*8 + 4];
            a0 += pj*va.x; a1 += pj*va.y; a2 += pj*va.z; a3 += pj*va.w;
            a4a += pj*vb.x; a5 += pj*vb.y; a6 += pj*vb.z; a7 += pj*vb.w;
        }
        float* dst = oh + ((size_t)((bm*4 + h)*2048 + (int)tq))*64 + fb*8;
        *(float4*)dst = make_float4(a0, a1, a2, a3);
        *(float4*)(dst + 4) = make_float4(a4a, a5, a6, a7);
    }
}

// ---------------- K5: combine hash rounds ----------------
__global__ __launch_bounds__(256) void k_combine(const float* __restrict__ oh,
    const float* __restrict__ logits, float* __restrict__ comb)
{
    int w = threadIdx.x >> 6, lane = threadIdx.x & 63;
    int row = blockIdx.x * 4 + w;                // bm*2048+t, 0..131071
    int bm = row >> 11, t = row & 2047;
    int b = bm >> 3, head = bm & 7;
    float l0 = logits[((size_t)(bm*4 + 0))*2048 + t];
    float l1 = logits[((size_t)(bm*4 + 1))*2048 + t];
    float l2 = logits[((size_t)(bm*4 + 2))*2048 + t];
    float l3 = logits[((size_t)(bm*4 + 3))*2048 + t];
    float m = fmaxf(fmaxf(l0, l1), fmaxf(l2, l3));
    float e0 = expf(l0 - m), e1 = expf(l1 - m), e2 = expf(l2 - m), e3 = expf(l3 - m);
    float inv = 1.0f / (e0 + e1 + e2 + e3);
    float o = 0.f;
    o += (e0*inv) * oh[((size_t)((bm*4+0)*2048 + t))*64 + lane];
    o += (e1*inv) * oh[((size_t)((bm*4+1)*2048 + t))*64 + lane];
    o += (e2*inv) * oh[((size_t)((bm*4+2)*2048 + t))*64 + lane];
    o += (e3*inv) * oh[((size_t)((bm*4+3)*2048 + t))*64 + lane];
    comb[((size_t)(b*2048 + t))*512 + head*64 + lane] = o;
}

// ---------------- K6: output GEMM + bias ----------------
__global__ __launch_bounds__(256) void k_gemm_out(
    const float* __restrict__ A, const float* __restrict__ Wout,
    const float* __restrict__ bias, float* __restrict__ out)
{
    __shared__ float As[32][68];
    __shared__ float Bs[32][68];
    const int bi = blockIdx.x;
    const int nt = bi & 7;           // 8 col tiles over N=512
    const int mt = bi >> 3;          // 256 row tiles
    const int m0 = mt * 64, n0 = nt * 64;
    const int tid = threadIdx.x;
    const int ty = tid >> 4, tx = tid & 15;
    float acc[4][4] = {};
    for (int k0 = 0; k0 < 512; k0 += 32) {
        #pragma unroll
        for (int c = 0; c < 2; c++) {
            int e = tid * 2 + c;
            int r = e >> 3, kq = e & 7;
            float4 a4 = *(const float4*)(A + (size_t)(m0 + r) * 512 + k0 + kq * 4);
            As[kq*4+0][r] = a4.x; As[kq*4+1][r] = a4.y;
            As[kq*4+2][r] = a4.z; As[kq*4+3][r] = a4.w;
            int kk = e >> 4, nq = e & 15;
            float4 b4 = *(const float4*)(Wout + (size_t)(k0 + kk) * 512 + n0 + nq * 4);
            *(float4*)&Bs[kk][nq*4] = b4;
        }
        __syncthreads();
        #pragma unroll
        for (int kk = 0; kk < 32; kk++) {
            float4 a4 = *(float4*)&As[kk][ty*4];
            float4 b4 = *(float4*)&Bs[kk][tx*4];
            float a_[4] = {a4.x, a4.y, a4.z, a4.w};
            float b_[4] = {b4.x, b4.y, b4.z, b4.w};
            #pragma unroll
            for (int i = 0; i < 4; i++)
                #pragma unroll
                for (int j = 0; j < 4; j++)
                    acc[i][j] += a_[i] * b_[j];
        }
        __syncthreads();
    }
    float4 bb = *(const float4*)(bias + n0 + tx*4);
    #pragma unroll
    for (int ri = 0; ri < 4; ri++) {
        int row = m0 + ty*4 + ri;
        float4 r4 = make_float4(acc[ri][0] + bb.x, acc[ri][1] + bb.y,
                                acc[ri][2] + bb.z, acc[ri][3] + bb.w);
        *(float4*)(out + (size_t)row * 512 + n0 + tx*4) = r4;
    }
}

extern "C" void kernel_launch(void* const* d_in, const int* in_sizes, int n_in,
                              void* d_out, int out_size, void* d_ws, size_t ws_size,
                              hipStream_t stream)
{
    const float* Q    = (const float*)d_in[0];
    const float* Wqk  = (const float*)d_in[3];
    const float* Wv   = (const float*)d_in[4];
    const float* Wout = (const float*)d_in[5];
    const float* bout = (const float*)d_in[6];
    const float* rot  = (const float*)d_in[7];
    float* ws = (float*)d_ws;
    float* qk     = ws;                       // 8,388,608
    float* vv     = ws + 8388608;             // 8,388,608
    float* oh     = ws + 16777216;            // 33,554,432
    float* comb   = ws + 50331648;            // 8,388,608
    float* rnorm  = ws + 58720256;            // 131,072
    float* logits = ws + 58851328;            // 524,288
    unsigned* buckets = (unsigned*)(ws + 59375616);   // 524,288
    unsigned* st      = (unsigned*)(ws + 59899904);   // 524,288
    float* out = (float*)d_out;

    k_gemm_qkv<<<dim3(4096), dim3(256), 0, stream>>>(Q, Wqk, Wv, qk, vv);
    k_rnorm  <<<dim3(32768), dim3(256), 0, stream>>>(qk, rnorm);
    k_hash   <<<dim3(2048), dim3(256), 0, stream>>>(qk, rot, buckets);
    k_sort   <<<dim3(256),  dim3(256), 0, stream>>>(buckets, st);
    k_attn   <<<dim3(8192), dim3(256), 0, stream>>>(qk, vv, rnorm, st, oh, logits);
    k_combine<<<dim3(32768), dim3(256), 0, stream>>>(oh, logits, comb);
    k_gemm_out<<<dim3(2048), dim3(256), 0, stream>>>(comb, Wout, bout, out);
}